// Round 11
// baseline (1785.424 us; speedup 1.0000x reference)
//
#include <hip/hip_runtime.h>
#include <stdint.h>

typedef unsigned short u16b;
typedef __attribute__((ext_vector_type(8))) __bf16 bf16x8;
typedef __attribute__((ext_vector_type(8))) unsigned short ushort8;
typedef __attribute__((ext_vector_type(4))) float f32x4;

#define B_    8
#define S_    2048
#define DIN_  512
#define DM_   1024
#define NL_   6
#define DOUT_ 512
#define MTOT  (B_ * S_)   // 16384

__device__ __forceinline__ u16b f2bf(float f) {
  unsigned u = __builtin_bit_cast(unsigned, f);
  u += 0x7fffu + ((u >> 16) & 1u);
  return (u16b)(u >> 16);
}
__device__ __forceinline__ float bf2f(u16b h) {
  return __builtin_bit_cast(float, (unsigned)h << 16);
}

// ---------------- PE table (float64 to match numpy promotion) ----------------
__global__ void pe_kernel(float* __restrict__ pe) {
  int idx = blockIdx.x * 256 + threadIdx.x;
  int s = idx >> 10, d = idx & 1023;
  int j = d >> 1;
  double div = exp(-log(10000.0) * (double)(2 * j) / 1024.0);
  double ang = (double)s * div;
  pe[idx] = (float)((d & 1) ? cos(ang) : sin(ang));
}

// ---------------- f32 -> bf16 flat convert ----------------
__global__ void cvt_bf16(const float* __restrict__ in, u16b* __restrict__ out, long long n) {
  long long i = (long long)blockIdx.x * 256 + threadIdx.x;
  long long st = (long long)gridDim.x * 256;
  for (; i < n; i += st) out[i] = f2bf(in[i]);
}

// ---------------- fused 3-way transpose f32 -> bf16, 64x64 tiles, vectorized ----------------
__global__ __launch_bounds__(256) void tr3v2(const float* __restrict__ q,
                                             const float* __restrict__ k,
                                             const float* __restrict__ v,
                                             u16b* __restrict__ oq, u16b* __restrict__ ok2,
                                             u16b* __restrict__ ov) {
  __shared__ float tile[64 * 65];   // +1 pad: readback bank = (8rq+j+c)%32, 2-way free
  const float* in = blockIdx.z == 0 ? q : (blockIdx.z == 1 ? k : v);
  u16b* out = blockIdx.z == 0 ? oq : (blockIdx.z == 1 ? ok2 : ov);
  int c0 = blockIdx.x * 64, r0 = blockIdx.y * 64;
  int t = threadIdx.x;
#pragma unroll
  for (int i = 0; i < 4; ++i) {
    int id = i * 256 + t;                 // 0..1023
    int r = id >> 4, cq = (id & 15) * 4;  // 16 float4 per 64-col row
    float4 val = *(const float4*)&in[(size_t)(r0 + r) * DM_ + c0 + cq];
    tile[r * 65 + cq + 0] = val.x;
    tile[r * 65 + cq + 1] = val.y;
    tile[r * 65 + cq + 2] = val.z;
    tile[r * 65 + cq + 3] = val.w;
  }
  __syncthreads();
#pragma unroll
  for (int i = 0; i < 2; ++i) {
    int id = i * 256 + t;                 // 0..511
    int c = id >> 3, rq = (id & 7) * 8;   // 8 ushort8 per 64-elem out row
    ushort8 o;
#pragma unroll
    for (int j = 0; j < 8; ++j) o[j] = f2bf(tile[(rq + j) * 65 + c]);
    *(ushort8*)&out[(size_t)(c0 + c) * DM_ + r0 + rq] = o;
  }
}

// ---------------- f32-score softmax (tier-C fallback): P = sm(A1) - 0.5*sm(A2) ----------------
__global__ __launch_bounds__(256) void softmax_combine(const float* __restrict__ A1,
                                                       const float* __restrict__ A2,
                                                       u16b* __restrict__ P,
                                                       long long pstride) {
  size_t row = blockIdx.x;
  const float* a1 = A1 + row * 2048;
  const float* a2 = A2 + row * 2048;
  u16b* p = P + row * pstride;
  int t = threadIdx.x, w = t >> 6, lane = t & 63;
  float v1[8], v2[8];
  float m1 = -3.4e38f, m2 = -3.4e38f;
#pragma unroll
  for (int i = 0; i < 8; ++i) {
    v1[i] = a1[i * 256 + t];
    v2[i] = a2[i * 256 + t];
    m1 = fmaxf(m1, v1[i]);
    m2 = fmaxf(m2, v2[i]);
  }
  __shared__ float red1[4], red2[4];
#pragma unroll
  for (int o = 32; o; o >>= 1) {
    m1 = fmaxf(m1, __shfl_xor(m1, o));
    m2 = fmaxf(m2, __shfl_xor(m2, o));
  }
  if (lane == 0) { red1[w] = m1; red2[w] = m2; }
  __syncthreads();
  m1 = fmaxf(fmaxf(red1[0], red1[1]), fmaxf(red1[2], red1[3]));
  m2 = fmaxf(fmaxf(red2[0], red2[1]), fmaxf(red2[2], red2[3]));
  float s1 = 0.f, s2 = 0.f;
#pragma unroll
  for (int i = 0; i < 8; ++i) {
    v1[i] = expf(v1[i] - m1);
    v2[i] = expf(v2[i] - m2);
    s1 += v1[i];
    s2 += v2[i];
  }
#pragma unroll
  for (int o = 32; o; o >>= 1) {
    s1 += __shfl_xor(s1, o);
    s2 += __shfl_xor(s2, o);
  }
  __syncthreads();
  if (lane == 0) { red1[w] = s1; red2[w] = s2; }
  __syncthreads();
  s1 = red1[0] + red1[1] + red1[2] + red1[3];
  s2 = red2[0] + red2[1] + red2[2] + red2[3];
  float i1 = 1.0f / s1, i2 = 0.5f / s2;
#pragma unroll
  for (int i = 0; i < 8; ++i)
    p[i * 256 + t] = f2bf(v1[i] * i1 - v2[i] * i2);
}

// ---------------- bf16-score softmax, all 16384 rows, P in-place over A1 ----------------
__global__ __launch_bounds__(256) void softmax_full(u16b* __restrict__ A1b,
                                                    const u16b* __restrict__ A2b) {
  size_t ro = (size_t)blockIdx.x * S_;
  u16b* a1 = A1b + ro;
  const u16b* a2 = A2b + ro;
  int t = threadIdx.x, w = t >> 6, lane = t & 63;
  ushort8 x1 = *(const ushort8*)&a1[t * 8];
  ushort8 x2 = *(const ushort8*)&a2[t * 8];
  float v1[8], v2[8];
  float m1 = -3.4e38f, m2 = -3.4e38f;
#pragma unroll
  for (int i = 0; i < 8; ++i) {
    v1[i] = bf2f(x1[i]);
    v2[i] = bf2f(x2[i]);
    m1 = fmaxf(m1, v1[i]);
    m2 = fmaxf(m2, v2[i]);
  }
  __shared__ float red1[4], red2[4];
#pragma unroll
  for (int o = 32; o; o >>= 1) {
    m1 = fmaxf(m1, __shfl_xor(m1, o));
    m2 = fmaxf(m2, __shfl_xor(m2, o));
  }
  if (lane == 0) { red1[w] = m1; red2[w] = m2; }
  __syncthreads();
  m1 = fmaxf(fmaxf(red1[0], red1[1]), fmaxf(red1[2], red1[3]));
  m2 = fmaxf(fmaxf(red2[0], red2[1]), fmaxf(red2[2], red2[3]));
  float s1 = 0.f, s2 = 0.f;
#pragma unroll
  for (int i = 0; i < 8; ++i) {
    v1[i] = expf(v1[i] - m1);
    v2[i] = expf(v2[i] - m2);
    s1 += v1[i];
    s2 += v2[i];
  }
#pragma unroll
  for (int o = 32; o; o >>= 1) {
    s1 += __shfl_xor(s1, o);
    s2 += __shfl_xor(s2, o);
  }
  __syncthreads();
  if (lane == 0) { red1[w] = s1; red2[w] = s2; }
  __syncthreads();
  s1 = red1[0] + red1[1] + red1[2] + red1[3];
  s2 = red2[0] + red2[1] + red2[2] + red2[3];
  float i1 = 1.0f / s1, i2 = 0.5f / s2;
  ushort8 outv;
#pragma unroll
  for (int i = 0; i < 8; ++i) outv[i] = f2bf(v1[i] * i1 - v2[i] * i2);
  *(ushort8*)&a1[t * 8] = outv;
}

#define GEPI_BF16      0
#define GEPI_BIAS      1
#define GEPI_BIAS_PE   2
#define GEPI_F32SCALE  3
#define GEPI_F32BIAS   4
#define GEPI_BF16_VT   5
#define GEPI_BF16SCALE 6
#define GEPI_QKV       7   // z<2: bf16 store (Q,K); z==2: V^T epilogue (vtb via pe slot)

// ---------------- 128x128 NT bf16 GEMM (proven m97-structure, tier-C + tail) ----------------
template <int EPI>
__global__ __launch_bounds__(256) void gemm_nt(
    const u16b* __restrict__ A, long long sAr, long long sAb,
    const u16b* __restrict__ Bt, long long sBr, long long sBb,
    void* __restrict__ Cv, long long sCr, long long sCb,
    int K, const float* __restrict__ bias, const float* __restrict__ pe, float alpha) {
  __shared__ __align__(16) u16b smem[16384];
  u16b* As = smem;
  u16b* Bs = smem + 8192;
  const int z = blockIdx.z;
  const u16b* Ab = A + (size_t)z * sAb;
  const u16b* Bb = Bt + (size_t)z * sBb;
  const int m0 = blockIdx.x * 128, n0 = blockIdx.y * 128;
  const int t = threadIdx.x;
  const int w = t >> 6, lane = t & 63;
  const int wr = w >> 1, wc = w & 1;
  const int lr = lane & 15, g0 = lane >> 4;

  f32x4 acc[4][4] = {};

  const int nkt = K >> 6;
  for (int kt = 0; kt < nkt; ++kt) {
#pragma unroll
    for (int i = 0; i < 4; ++i) {
      int c = i * 256 + t;
      int r = c >> 3, cc = c & 7;
      int gc = cc ^ (r & 7);
      const u16b* ga = Ab + (size_t)(m0 + r) * sAr + kt * 64 + gc * 8;
      const u16b* gb = Bb + (size_t)(n0 + r) * sBr + kt * 64 + gc * 8;
      u16b* la = &As[(i * 256 + w * 64) * 8];
      u16b* lb = &Bs[(i * 256 + w * 64) * 8];
      __builtin_amdgcn_global_load_lds((__attribute__((address_space(1))) void*)ga,
                                       (__attribute__((address_space(3))) void*)la, 16, 0, 0);
      __builtin_amdgcn_global_load_lds((__attribute__((address_space(1))) void*)gb,
                                       (__attribute__((address_space(3))) void*)lb, 16, 0, 0);
    }
    __syncthreads();
#pragma unroll
    for (int kk = 0; kk < 2; ++kk) {
      bf16x8 af[4], bfr[4];
#pragma unroll
      for (int m = 0; m < 4; ++m) {
        int r = wr * 64 + m * 16 + lr;
        int sidx = (kk * 4 + g0) ^ (r & 7);
        af[m] = *(const bf16x8*)&As[(r * 8 + sidx) * 8];
      }
#pragma unroll
      for (int n = 0; n < 4; ++n) {
        int r = wc * 64 + n * 16 + lr;
        int sidx = (kk * 4 + g0) ^ (r & 7);
        bfr[n] = *(const bf16x8*)&Bs[(r * 8 + sidx) * 8];
      }
#pragma unroll
      for (int m = 0; m < 4; ++m)
#pragma unroll
        for (int n = 0; n < 4; ++n)
          acc[m][n] = __builtin_amdgcn_mfma_f32_16x16x32_bf16(af[m], bfr[n], acc[m][n], 0, 0, 0);
    }
    __syncthreads();
  }

  u16b* Ch = (u16b*)Cv;
  float* Cf = (float*)Cv;
  const size_t cb = (size_t)z * sCb;
#pragma unroll
  for (int m = 0; m < 4; ++m) {
#pragma unroll
    for (int j = 0; j < 4; ++j) {
      int r = m0 + wr * 64 + m * 16 + g0 * 4 + j;
      size_t ro = cb + (size_t)r * sCr;
#pragma unroll
      for (int n = 0; n < 4; ++n) {
        int c = n0 + wc * 64 + n * 16 + lr;
        float v = acc[m][n][j];
        if constexpr (EPI == GEPI_BF16) Ch[ro + c] = f2bf(v);
        else if constexpr (EPI == GEPI_BIAS) Ch[ro + c] = f2bf(v + bias[c]);
        else if constexpr (EPI == GEPI_BIAS_PE)
          Ch[ro + c] = f2bf(v + bias[c] + pe[(size_t)(r & (S_ - 1)) * DM_ + c]);
        else if constexpr (EPI == GEPI_F32SCALE) Cf[ro + c] = v * alpha;
        else Cf[ro + c] = v + bias[c];
      }
    }
  }
}

// ---------------- 256x256 NT bf16 GEMM, 8 waves, R4/R8-proven prefetch pipeline ----------------
// offsets: Xb = X + (z>>1)*sXb2 + (z&1)*sXb  (A, B, and C all use this form)
template <int EPI>
__global__ __launch_bounds__(512, 1) void gemm8(
    const u16b* __restrict__ A, long long sAr, long long sAb, long long sAb2,
    const u16b* __restrict__ Bt, long long sBr, long long sBb, long long sBb2,
    void* __restrict__ Cv, long long sCr, long long sCb, long long sCb2,
    int K, const float* __restrict__ bias, const float* __restrict__ pe, float alpha) {
  extern __shared__ __align__(16) u16b lds[];   // 2 bufs x (A 256x64 + B 256x64) = 128 KB
  const int z = blockIdx.z;
  const u16b* Ab = A + (size_t)(z >> 1) * sAb2 + (size_t)(z & 1) * sAb;
  const u16b* Bb = Bt + (size_t)(z >> 1) * sBb2 + (size_t)(z & 1) * sBb;
  const int m0 = blockIdx.x * 256, n0 = blockIdx.y * 256;
  const int t = threadIdx.x;
  const int wid = t >> 6, lane = t & 63;
  const int wr = wid >> 2, wc = wid & 3;          // 2 x 4 wave grid; per-wave out 128x64
  const int lr = lane & 15, g0 = lane >> 4;

  f32x4 acc[8][4] = {};
  const int nkt = K >> 6;

  auto stage = [&](int kt, int buf) {   // 8 global_load_lds x 16B per thread
    u16b* bufA = lds + buf * 32768;
    u16b* bufB = bufA + 16384;
#pragma unroll
    for (int i = 0; i < 4; ++i) {
      int id = i * 512 + t;
      int r = id >> 3, cc = id & 7;
      int gc = cc ^ (r & 7);   // pre-swizzled source; re-applied on read
      const u16b* ga = Ab + (size_t)(m0 + r) * sAr + kt * 64 + gc * 8;
      const u16b* gb = Bb + (size_t)(n0 + r) * sBr + kt * 64 + gc * 8;
      u16b* la = bufA + (i * 512 + wid * 64) * 8;
      u16b* lb = bufB + (i * 512 + wid * 64) * 8;
      __builtin_amdgcn_global_load_lds((__attribute__((address_space(1))) void*)ga,
                                       (__attribute__((address_space(3))) void*)la, 16, 0, 0);
      __builtin_amdgcn_global_load_lds((__attribute__((address_space(1))) void*)gb,
                                       (__attribute__((address_space(3))) void*)lb, 16, 0, 0);
    }
  };

  // prologue: tile 0 -> buf 0
  stage(0, 0);
  __builtin_amdgcn_sched_barrier(0);
  asm volatile("s_waitcnt vmcnt(0)" ::: "memory");
  __builtin_amdgcn_sched_barrier(0);
  __builtin_amdgcn_s_barrier();
  __builtin_amdgcn_sched_barrier(0);

  for (int kt = 0; kt < nkt; ++kt) {
    const int cur = kt & 1;
    // prefetch next tile FIRST: its HBM latency hides under this tile's 64 MFMA
    if (kt + 1 < nkt) stage(kt + 1, cur ^ 1);
    __builtin_amdgcn_sched_barrier(0);
    const u16b* bufA = lds + cur * 32768;
    const u16b* bufB = bufA + 16384;
#pragma unroll
    for (int kk = 0; kk < 2; ++kk) {
      bf16x8 af[8], bfr[4];
#pragma unroll
      for (int m = 0; m < 8; ++m) {
        int r = wr * 128 + m * 16 + lr;
        int sidx = (kk * 4 + g0) ^ (r & 7);
        af[m] = *(const bf16x8*)&bufA[(r * 8 + sidx) * 8];
      }
#pragma unroll
      for (int n = 0; n < 4; ++n) {
        int r = wc * 64 + n * 16 + lr;
        int sidx = (kk * 4 + g0) ^ (r & 7);
        bfr[n] = *(const bf16x8*)&bufB[(r * 8 + sidx) * 8];
      }
#pragma unroll
      for (int m = 0; m < 8; ++m)
#pragma unroll
        for (int n = 0; n < 4; ++n)
          acc[m][n] = __builtin_amdgcn_mfma_f32_16x16x32_bf16(af[m], bfr[n], acc[m][n], 0, 0, 0);
    }
    // drain own prefetch loads, then raw barrier (no compiler full-drain)
    __builtin_amdgcn_sched_barrier(0);
    asm volatile("s_waitcnt vmcnt(0)" ::: "memory");
    __builtin_amdgcn_sched_barrier(0);
    __builtin_amdgcn_s_barrier();
    __builtin_amdgcn_sched_barrier(0);
  }

  // V^T epilogue: acc -> LDS (transposed, XOR-swizzled) -> coalesced write [batch][col][row]
  const bool doVT = (EPI == GEPI_BF16_VT) || (EPI == GEPI_QKV && z == 2);
  if (doVT) {
    u16b* tile = lds;
    u16b* vtb = (EPI == GEPI_QKV) ? (u16b*)(void*)pe : (u16b*)Cv;
#pragma unroll
    for (int m = 0; m < 8; ++m)
#pragma unroll
      for (int j = 0; j < 4; ++j) {
        int rl = wr * 128 + m * 16 + g0 * 4 + j;
#pragma unroll
        for (int n = 0; n < 4; ++n) {
          int cl = wc * 64 + n * 16 + lr;
          tile[cl * 256 + (rl ^ ((cl & 7) << 3))] = f2bf(acc[m][n][j]);
        }
      }
    __syncthreads();
    const int batch = m0 >> 11;
    const int r0b = m0 & (S_ - 1);
    u16b* obase = vtb + (size_t)batch * DM_ * S_ + r0b;
#pragma unroll
    for (int it = 0; it < 16; ++it) {
      int id = it * 512 + t;
      int c = id >> 5, rc = id & 31;
      *(bf16x8*)&obase[(size_t)(n0 + c) * S_ + rc * 8] =
          *(const bf16x8*)&tile[c * 256 + ((rc * 8) ^ ((c & 7) << 3))];
    }
    return;
  }

  u16b* Ch = (u16b*)Cv;
  float* Cf = (float*)Cv;
  const size_t cb = (size_t)(z >> 1) * sCb2 + (size_t)(z & 1) * sCb;
#pragma unroll
  for (int m = 0; m < 8; ++m) {
#pragma unroll
    for (int j = 0; j < 4; ++j) {
      int r = m0 + wr * 128 + m * 16 + g0 * 4 + j;
      size_t ro = cb + (size_t)r * sCr;
#pragma unroll
      for (int n = 0; n < 4; ++n) {
        int c = n0 + wc * 64 + n * 16 + lr;
        float v = acc[m][n][j];
        if constexpr (EPI == GEPI_BF16 || EPI == GEPI_QKV) Ch[ro + c] = f2bf(v);
        else if constexpr (EPI == GEPI_BIAS) Ch[ro + c] = f2bf(v + bias[c]);
        else if constexpr (EPI == GEPI_BIAS_PE)
          Ch[ro + c] = f2bf(v + bias[c] + pe[(size_t)(r & (S_ - 1)) * DM_ + c]);
        else if constexpr (EPI == GEPI_F32SCALE) Cf[ro + c] = v * alpha;
        else if constexpr (EPI == GEPI_BF16SCALE) Ch[ro + c] = f2bf(v * alpha);
        else Cf[ro + c] = v + bias[c];
      }
    }
  }
}

extern "C" void kernel_launch(void* const* d_in, const int* in_sizes, int n_in,
                              void* d_out, int out_size, void* d_ws, size_t ws_size,
                              hipStream_t stream) {
  const float* x     = (const float*)d_in[0];
  const float* W_in  = (const float*)d_in[1];
  const float* b_in  = (const float*)d_in[2];
  const float* W_ctx = (const float*)d_in[3];
  const float* b_ctx = (const float*)d_in[4];
  const float* Wq    = (const float*)d_in[5];
  const float* Wk    = (const float*)d_in[6];
  const float* Wv    = (const float*)d_in[7];
  const float* W_out = (const float*)d_in[8];
  const float* b_out = (const float*)d_in[9];
  float* out = (float*)d_out;

  const int LDS8 = 131072;
  hipFuncSetAttribute((const void*)gemm8<GEPI_BF16>,
                      hipFuncAttributeMaxDynamicSharedMemorySize, LDS8);
  hipFuncSetAttribute((const void*)gemm8<GEPI_BIAS>,
                      hipFuncAttributeMaxDynamicSharedMemorySize, LDS8);
  hipFuncSetAttribute((const void*)gemm8<GEPI_BIAS_PE>,
                      hipFuncAttributeMaxDynamicSharedMemorySize, LDS8);
  hipFuncSetAttribute((const void*)gemm8<GEPI_QKV>,
                      hipFuncAttributeMaxDynamicSharedMemorySize, LDS8);
  hipFuncSetAttribute((const void*)gemm8<GEPI_BF16SCALE>,
                      hipFuncAttributeMaxDynamicSharedMemorySize, LDS8);

  const size_t SZ_A12 = (size_t)2 * S_ * S_ * 4;       // 32 MB
  const size_t SZ_PF  = (size_t)B_ * S_ * S_ * 2;      // 64 MB full-batch bf16 P / A1
  const size_t SZ_H   = (size_t)MTOT * DM_ * 2;        // 32 MB
  const size_t SZ_WIN = (size_t)DM_ * DIN_ * 2;
  const size_t SZ_WX  = (size_t)DM_ * DM_ * 2;
  const size_t SZ_WO  = (size_t)DOUT_ * DM_ * 2;
  const size_t SZ_WL  = (size_t)3 * DM_ * DM_ * 2;
  const size_t SLACK  = 65536;
  const size_t needB = SZ_A12 + SZ_PF + 4 * SZ_H + SZ_WO + SZ_WL + SLACK;             // ~231.1 MB
  const size_t needC = SZ_A12 + 4 * SZ_H + SZ_WIN + SZ_WX + SZ_WO + SZ_WL + SLACK;    // ~170.1 MB
  bool fullP = ws_size >= needB;
  if (ws_size < needC) return;

  char* wsp = (char*)d_ws;
  size_t off = 0;
  auto alloc = [&](size_t bytes) -> void* {
    void* p = wsp + off;
    off += (bytes + 255) & ~(size_t)255;
    return p;
  };
  // fullP layout: Pfull | A12 | hbuf contiguous:
  //   A1 (8 batches bf16) -> Pfull (in-place softmax -> P)
  //   A2 (8 batches bf16) -> A12+hbuf (64 MB contiguous, both dead during scores)
  u16b* Pfull = fullP ? (u16b*)alloc(SZ_PF) : nullptr;
  float* A12  = (float*)alloc(SZ_A12);
  u16b* hbuf  = (u16b*)alloc(SZ_H);
  u16b* qbuf  = (u16b*)alloc(SZ_H);
  u16b* kbuf  = (u16b*)alloc(SZ_H);
  u16b* vtb   = (u16b*)alloc(SZ_H);
  u16b *winb, *wctxb;
  if (fullP) {   // head weights alias Pfull (dead until layer-0 scores)
    winb  = (u16b*)Pfull;
    wctxb = (u16b*)((char*)Pfull + SZ_WIN);
  } else {
    winb  = (u16b*)alloc(SZ_WIN);
    wctxb = (u16b*)alloc(SZ_WX);
  }
  u16b* woutb = (u16b*)alloc(SZ_WO);
  u16b* wTl   = (u16b*)alloc(SZ_WL);

  // xbf + pe alias A12 (dead before the attention phase)
  u16b* xbf = (u16b*)A12;
  float* pe = (float*)((char*)A12 + (size_t)MTOT * DIN_ * 2);
  float* A1f = A12;
  float* A2f = A12 + (size_t)S_ * S_;
  u16b* A2u  = (u16b*)A12;      // bf16 A2 region (spans A12+hbuf, 64 MB)

  const size_t WSTEP = (size_t)DM_ * DM_;
  u16b* wqTl = wTl;
  u16b* wkTl = wTl + WSTEP;
  u16b* wvTl = wTl + 2 * WSTEP;

  dim3 blk(256);

  pe_kernel<<<dim3((S_ * DM_) / 256), blk, 0, stream>>>(pe);
  cvt_bf16<<<dim3(2048), blk, 0, stream>>>(x, xbf, (long long)MTOT * DIN_);
  cvt_bf16<<<dim3(512), blk, 0, stream>>>(W_in, winb, (long long)DM_ * DIN_);
  cvt_bf16<<<dim3(1024), blk, 0, stream>>>(W_ctx, wctxb, (long long)DM_ * DM_);
  cvt_bf16<<<dim3(512), blk, 0, stream>>>(W_out, woutb, (long long)DOUT_ * DM_);

  // h1 = x @ W_in^T + b_in -> qbuf ; h = h1 @ W_ctx^T + b_ctx + PE -> hbuf
  gemm8<GEPI_BIAS><<<dim3(MTOT / 256, DM_ / 256, 1), dim3(512), LDS8, stream>>>(
      xbf, DIN_, 0, 0, winb, DIN_, 0, 0, qbuf, DM_, 0, 0, DIN_, b_in, nullptr, 1.0f);
  gemm8<GEPI_BIAS_PE><<<dim3(MTOT / 256, DM_ / 256, 1), dim3(512), LDS8, stream>>>(
      qbuf, DM_, 0, 0, wctxb, DM_, 0, 0, hbuf, DM_, 0, 0, DM_, b_ctx, pe, 1.0f);

  for (int l = 0; l < NL_; ++l) {
    tr3v2<<<dim3(DM_ / 64, DM_ / 64, 3), blk, 0, stream>>>(
        Wq + (size_t)l * WSTEP, Wk + (size_t)l * WSTEP, Wv + (size_t)l * WSTEP,
        wqTl, wkTl, wvTl);
    // Q, K, V projections in ONE z=3 launch (768 blocks = 3 full machine waves):
    // z=0 -> qbuf, z=1 -> kbuf (normal store); z=2 -> V^T epilogue to vtb (via pe slot)
    gemm8<GEPI_QKV><<<dim3(MTOT / 256, DM_ / 256, 3), dim3(512), LDS8, stream>>>(
        hbuf, DM_, 0, 0, wqTl, DM_, (long long)WSTEP, 2 * (long long)WSTEP,
        qbuf, DM_, (long long)(kbuf - qbuf), 0, DM_, nullptr, (const float*)vtb, 1.0f);

    if (fullP) {
      // all scores in ONE z=16 launch (1024 blocks): z=2b+half;
      // A1[b] -> Pfull + b*S*S, A2[b] -> A2u + b*S*S (spans A12|hbuf, both dead here)
      gemm8<GEPI_BF16SCALE><<<dim3(S_ / 256, S_ / 256, 16), dim3(512), LDS8, stream>>>(
          qbuf, DM_, DM_ / 2, (long long)S_ * DM_,
          kbuf, DM_, DM_ / 2, (long long)S_ * DM_,
          Pfull, S_, (long long)(A2u - Pfull), (long long)S_ * S_,
          DM_ / 2, nullptr, nullptr, 0.03125f);
      // one softmax over all 16384 rows; P in-place over A1 (Pfull)
      softmax_full<<<dim3(MTOT), blk, 0, stream>>>(Pfull, A2u);
      // h = P @ V, all batches in one 256-block launch
      gemm8<GEPI_BF16><<<dim3(S_ / 256, DM_ / 256, B_), dim3(512), LDS8, stream>>>(
          Pfull, S_, (long long)S_ * S_, 2 * (long long)S_ * S_,
          vtb, S_, (long long)DM_ * S_, 2 * (long long)DM_ * S_,
          hbuf, DM_, (long long)S_ * DM_, 2 * (long long)S_ * DM_,
          S_, nullptr, nullptr, 1.0f);
    } else {
      for (int b = 0; b < B_; ++b) {
        const u16b* qb = qbuf + (size_t)b * S_ * DM_;
        const u16b* kb = kbuf + (size_t)b * S_ * DM_;
        gemm_nt<GEPI_F32SCALE><<<dim3(S_ / 128, S_ / 128, 2), blk, 0, stream>>>(
            qb, DM_, DM_ / 2, kb, DM_, DM_ / 2,
            A1f, S_, (long long)S_ * S_, DM_ / 2, nullptr, nullptr, 0.03125f);
        softmax_combine<<<dim3(S_), blk, 0, stream>>>(A1f, A2f, (u16b*)A1f, 2 * S_);
        gemm_nt<GEPI_BF16><<<dim3(S_ / 128, DM_ / 128, 1), blk, 0, stream>>>(
            (u16b*)A1f, 2 * S_, 0, vtb + (size_t)b * DM_ * S_, S_, 0,
            hbuf + (size_t)b * S_ * DM_, DM_, 0, S_, nullptr, nullptr, 1.0f);
      }
    }
  }

  // out = h @ W_out^T + b_out (fp32)
  gemm_nt<GEPI_F32BIAS><<<dim3(MTOT / 128, DOUT_ / 128, 1), blk, 0, stream>>>(
      hbuf, DM_, 0, woutb, DM_, 0, out, DOUT_, 0, DM_, b_out, nullptr, 1.0f);
}

// Round 12
// 1767.128 us; speedup vs baseline: 1.0104x; 1.0104x over previous
//
#include <hip/hip_runtime.h>
#include <stdint.h>

typedef unsigned short u16b;
typedef __attribute__((ext_vector_type(8))) __bf16 bf16x8;
typedef __attribute__((ext_vector_type(8))) unsigned short ushort8;
typedef __attribute__((ext_vector_type(4))) float f32x4;

#define B_    8
#define S_    2048
#define DIN_  512
#define DM_   1024
#define NL_   6
#define DOUT_ 512
#define MTOT  (B_ * S_)   // 16384

__device__ __forceinline__ u16b f2bf(float f) {
  unsigned u = __builtin_bit_cast(unsigned, f);
  u += 0x7fffu + ((u >> 16) & 1u);
  return (u16b)(u >> 16);
}
__device__ __forceinline__ float bf2f(u16b h) {
  return __builtin_bit_cast(float, (unsigned)h << 16);
}

// ---------------- PE table (float64 to match numpy promotion) ----------------
__global__ void pe_kernel(float* __restrict__ pe) {
  int idx = blockIdx.x * 256 + threadIdx.x;
  int s = idx >> 10, d = idx & 1023;
  int j = d >> 1;
  double div = exp(-log(10000.0) * (double)(2 * j) / 1024.0);
  double ang = (double)s * div;
  pe[idx] = (float)((d & 1) ? cos(ang) : sin(ang));
}

// ---------------- f32 -> bf16 flat convert ----------------
__global__ void cvt_bf16(const float* __restrict__ in, u16b* __restrict__ out, long long n) {
  long long i = (long long)blockIdx.x * 256 + threadIdx.x;
  long long st = (long long)gridDim.x * 256;
  for (; i < n; i += st) out[i] = f2bf(in[i]);
}

// ---------------- fused 3-way transpose f32 -> bf16, 64x64 tiles, vectorized ----------------
__global__ __launch_bounds__(256) void tr3v2(const float* __restrict__ q,
                                             const float* __restrict__ k,
                                             const float* __restrict__ v,
                                             u16b* __restrict__ oq, u16b* __restrict__ ok2,
                                             u16b* __restrict__ ov) {
  __shared__ float tile[64 * 65];   // +1 pad: readback bank = (8rq+j+c)%32, 2-way free
  const float* in = blockIdx.z == 0 ? q : (blockIdx.z == 1 ? k : v);
  u16b* out = blockIdx.z == 0 ? oq : (blockIdx.z == 1 ? ok2 : ov);
  int c0 = blockIdx.x * 64, r0 = blockIdx.y * 64;
  int t = threadIdx.x;
#pragma unroll
  for (int i = 0; i < 4; ++i) {
    int id = i * 256 + t;                 // 0..1023
    int r = id >> 4, cq = (id & 15) * 4;  // 16 float4 per 64-col row
    float4 val = *(const float4*)&in[(size_t)(r0 + r) * DM_ + c0 + cq];
    tile[r * 65 + cq + 0] = val.x;
    tile[r * 65 + cq + 1] = val.y;
    tile[r * 65 + cq + 2] = val.z;
    tile[r * 65 + cq + 3] = val.w;
  }
  __syncthreads();
#pragma unroll
  for (int i = 0; i < 2; ++i) {
    int id = i * 256 + t;                 // 0..511
    int c = id >> 3, rq = (id & 7) * 8;   // 8 ushort8 per 64-elem out row
    ushort8 o;
#pragma unroll
    for (int j = 0; j < 8; ++j) o[j] = f2bf(tile[(rq + j) * 65 + c]);
    *(ushort8*)&out[(size_t)(c0 + c) * DM_ + r0 + rq] = o;
  }
}

// ---------------- f32-score softmax (tier-C fallback): P = sm(A1) - 0.5*sm(A2) ----------------
__global__ __launch_bounds__(256) void softmax_combine(const float* __restrict__ A1,
                                                       const float* __restrict__ A2,
                                                       u16b* __restrict__ P,
                                                       long long pstride) {
  size_t row = blockIdx.x;
  const float* a1 = A1 + row * 2048;
  const float* a2 = A2 + row * 2048;
  u16b* p = P + row * pstride;
  int t = threadIdx.x, w = t >> 6, lane = t & 63;
  float v1[8], v2[8];
  float m1 = -3.4e38f, m2 = -3.4e38f;
#pragma unroll
  for (int i = 0; i < 8; ++i) {
    v1[i] = a1[i * 256 + t];
    v2[i] = a2[i * 256 + t];
    m1 = fmaxf(m1, v1[i]);
    m2 = fmaxf(m2, v2[i]);
  }
  __shared__ float red1[4], red2[4];
#pragma unroll
  for (int o = 32; o; o >>= 1) {
    m1 = fmaxf(m1, __shfl_xor(m1, o));
    m2 = fmaxf(m2, __shfl_xor(m2, o));
  }
  if (lane == 0) { red1[w] = m1; red2[w] = m2; }
  __syncthreads();
  m1 = fmaxf(fmaxf(red1[0], red1[1]), fmaxf(red1[2], red1[3]));
  m2 = fmaxf(fmaxf(red2[0], red2[1]), fmaxf(red2[2], red2[3]));
  float s1 = 0.f, s2 = 0.f;
#pragma unroll
  for (int i = 0; i < 8; ++i) {
    v1[i] = expf(v1[i] - m1);
    v2[i] = expf(v2[i] - m2);
    s1 += v1[i];
    s2 += v2[i];
  }
#pragma unroll
  for (int o = 32; o; o >>= 1) {
    s1 += __shfl_xor(s1, o);
    s2 += __shfl_xor(s2, o);
  }
  __syncthreads();
  if (lane == 0) { red1[w] = s1; red2[w] = s2; }
  __syncthreads();
  s1 = red1[0] + red1[1] + red1[2] + red1[3];
  s2 = red2[0] + red2[1] + red2[2] + red2[3];
  float i1 = 1.0f / s1, i2 = 0.5f / s2;
#pragma unroll
  for (int i = 0; i < 8; ++i)
    p[i * 256 + t] = f2bf(v1[i] * i1 - v2[i] * i2);
}

// ---------------- bf16-score softmax, all 16384 rows, P in-place over A1 ----------------
__global__ __launch_bounds__(256) void softmax_full(u16b* __restrict__ A1b,
                                                    const u16b* __restrict__ A2b) {
  size_t ro = (size_t)blockIdx.x * S_;
  u16b* a1 = A1b + ro;
  const u16b* a2 = A2b + ro;
  int t = threadIdx.x, w = t >> 6, lane = t & 63;
  ushort8 x1 = *(const ushort8*)&a1[t * 8];
  ushort8 x2 = *(const ushort8*)&a2[t * 8];
  float v1[8], v2[8];
  float m1 = -3.4e38f, m2 = -3.4e38f;
#pragma unroll
  for (int i = 0; i < 8; ++i) {
    v1[i] = bf2f(x1[i]);
    v2[i] = bf2f(x2[i]);
    m1 = fmaxf(m1, v1[i]);
    m2 = fmaxf(m2, v2[i]);
  }
  __shared__ float red1[4], red2[4];
#pragma unroll
  for (int o = 32; o; o >>= 1) {
    m1 = fmaxf(m1, __shfl_xor(m1, o));
    m2 = fmaxf(m2, __shfl_xor(m2, o));
  }
  if (lane == 0) { red1[w] = m1; red2[w] = m2; }
  __syncthreads();
  m1 = fmaxf(fmaxf(red1[0], red1[1]), fmaxf(red1[2], red1[3]));
  m2 = fmaxf(fmaxf(red2[0], red2[1]), fmaxf(red2[2], red2[3]));
  float s1 = 0.f, s2 = 0.f;
#pragma unroll
  for (int i = 0; i < 8; ++i) {
    v1[i] = expf(v1[i] - m1);
    v2[i] = expf(v2[i] - m2);
    s1 += v1[i];
    s2 += v2[i];
  }
#pragma unroll
  for (int o = 32; o; o >>= 1) {
    s1 += __shfl_xor(s1, o);
    s2 += __shfl_xor(s2, o);
  }
  __syncthreads();
  if (lane == 0) { red1[w] = s1; red2[w] = s2; }
  __syncthreads();
  s1 = red1[0] + red1[1] + red1[2] + red1[3];
  s2 = red2[0] + red2[1] + red2[2] + red2[3];
  float i1 = 1.0f / s1, i2 = 0.5f / s2;
  ushort8 outv;
#pragma unroll
  for (int i = 0; i < 8; ++i) outv[i] = f2bf(v1[i] * i1 - v2[i] * i2);
  *(ushort8*)&a1[t * 8] = outv;
}

#define GEPI_BF16      0
#define GEPI_BIAS      1
#define GEPI_BIAS_PE   2
#define GEPI_F32SCALE  3
#define GEPI_F32BIAS   4
#define GEPI_BF16_VT   5
#define GEPI_BF16SCALE 6
#define GEPI_QKV       7   // z<2: bf16 store (Q,K); z==2: V^T epilogue (vtb via pe slot)

// ---------------- 128x128 NT bf16 GEMM (proven m97-structure, tier-C + tail) ----------------
template <int EPI>
__global__ __launch_bounds__(256) void gemm_nt(
    const u16b* __restrict__ A, long long sAr, long long sAb,
    const u16b* __restrict__ Bt, long long sBr, long long sBb,
    void* __restrict__ Cv, long long sCr, long long sCb,
    int K, const float* __restrict__ bias, const float* __restrict__ pe, float alpha) {
  __shared__ __align__(16) u16b smem[16384];
  u16b* As = smem;
  u16b* Bs = smem + 8192;
  const int z = blockIdx.z;
  const u16b* Ab = A + (size_t)z * sAb;
  const u16b* Bb = Bt + (size_t)z * sBb;
  const int m0 = blockIdx.x * 128, n0 = blockIdx.y * 128;
  const int t = threadIdx.x;
  const int w = t >> 6, lane = t & 63;
  const int wr = w >> 1, wc = w & 1;
  const int lr = lane & 15, g0 = lane >> 4;

  f32x4 acc[4][4] = {};

  const int nkt = K >> 6;
  for (int kt = 0; kt < nkt; ++kt) {
#pragma unroll
    for (int i = 0; i < 4; ++i) {
      int c = i * 256 + t;
      int r = c >> 3, cc = c & 7;
      int gc = cc ^ (r & 7);
      const u16b* ga = Ab + (size_t)(m0 + r) * sAr + kt * 64 + gc * 8;
      const u16b* gb = Bb + (size_t)(n0 + r) * sBr + kt * 64 + gc * 8;
      u16b* la = &As[(i * 256 + w * 64) * 8];
      u16b* lb = &Bs[(i * 256 + w * 64) * 8];
      __builtin_amdgcn_global_load_lds((__attribute__((address_space(1))) void*)ga,
                                       (__attribute__((address_space(3))) void*)la, 16, 0, 0);
      __builtin_amdgcn_global_load_lds((__attribute__((address_space(1))) void*)gb,
                                       (__attribute__((address_space(3))) void*)lb, 16, 0, 0);
    }
    __syncthreads();
#pragma unroll
    for (int kk = 0; kk < 2; ++kk) {
      bf16x8 af[4], bfr[4];
#pragma unroll
      for (int m = 0; m < 4; ++m) {
        int r = wr * 64 + m * 16 + lr;
        int sidx = (kk * 4 + g0) ^ (r & 7);
        af[m] = *(const bf16x8*)&As[(r * 8 + sidx) * 8];
      }
#pragma unroll
      for (int n = 0; n < 4; ++n) {
        int r = wc * 64 + n * 16 + lr;
        int sidx = (kk * 4 + g0) ^ (r & 7);
        bfr[n] = *(const bf16x8*)&Bs[(r * 8 + sidx) * 8];
      }
#pragma unroll
      for (int m = 0; m < 4; ++m)
#pragma unroll
        for (int n = 0; n < 4; ++n)
          acc[m][n] = __builtin_amdgcn_mfma_f32_16x16x32_bf16(af[m], bfr[n], acc[m][n], 0, 0, 0);
    }
    __syncthreads();
  }

  u16b* Ch = (u16b*)Cv;
  float* Cf = (float*)Cv;
  const size_t cb = (size_t)z * sCb;
#pragma unroll
  for (int m = 0; m < 4; ++m) {
#pragma unroll
    for (int j = 0; j < 4; ++j) {
      int r = m0 + wr * 64 + m * 16 + g0 * 4 + j;
      size_t ro = cb + (size_t)r * sCr;
#pragma unroll
      for (int n = 0; n < 4; ++n) {
        int c = n0 + wc * 64 + n * 16 + lr;
        float v = acc[m][n][j];
        if constexpr (EPI == GEPI_BF16) Ch[ro + c] = f2bf(v);
        else if constexpr (EPI == GEPI_BIAS) Ch[ro + c] = f2bf(v + bias[c]);
        else if constexpr (EPI == GEPI_BIAS_PE)
          Ch[ro + c] = f2bf(v + bias[c] + pe[(size_t)(r & (S_ - 1)) * DM_ + c]);
        else if constexpr (EPI == GEPI_F32SCALE) Cf[ro + c] = v * alpha;
        else Cf[ro + c] = v + bias[c];
      }
    }
  }
}

// ---------------- 256x256 NT bf16 GEMM, 8 waves, R4/R8/R10-proven prefetch pipeline ----------------
// offsets: Xb = X + (z>>1)*sXb2 + (z&1)*sXb  (A, B, and C all use this form)
template <int EPI>
__global__ __launch_bounds__(512, 1) void gemm8(
    const u16b* __restrict__ A, long long sAr, long long sAb, long long sAb2,
    const u16b* __restrict__ Bt, long long sBr, long long sBb, long long sBb2,
    void* __restrict__ Cv, long long sCr, long long sCb, long long sCb2,
    int K, const float* __restrict__ bias, const float* __restrict__ pe, float alpha) {
  extern __shared__ __align__(16) u16b lds[];   // 2 bufs x (A 256x64 + B 256x64) = 128 KB
  const int z = blockIdx.z;
  const u16b* Ab = A + (size_t)(z >> 1) * sAb2 + (size_t)(z & 1) * sAb;
  const u16b* Bb = Bt + (size_t)(z >> 1) * sBb2 + (size_t)(z & 1) * sBb;
  const int m0 = blockIdx.x * 256, n0 = blockIdx.y * 256;
  const int t = threadIdx.x;
  const int wid = t >> 6, lane = t & 63;
  const int wr = wid >> 2, wc = wid & 3;          // 2 x 4 wave grid; per-wave out 128x64
  const int lr = lane & 15, g0 = lane >> 4;

  f32x4 acc[8][4] = {};
  const int nkt = K >> 6;

  auto stage = [&](int kt, int buf) {   // 8 global_load_lds x 16B per thread
    u16b* bufA = lds + buf * 32768;
    u16b* bufB = bufA + 16384;
#pragma unroll
    for (int i = 0; i < 4; ++i) {
      int id = i * 512 + t;
      int r = id >> 3, cc = id & 7;
      int gc = cc ^ (r & 7);   // pre-swizzled source; re-applied on read
      const u16b* ga = Ab + (size_t)(m0 + r) * sAr + kt * 64 + gc * 8;
      const u16b* gb = Bb + (size_t)(n0 + r) * sBr + kt * 64 + gc * 8;
      u16b* la = bufA + (i * 512 + wid * 64) * 8;
      u16b* lb = bufB + (i * 512 + wid * 64) * 8;
      __builtin_amdgcn_global_load_lds((__attribute__((address_space(1))) void*)ga,
                                       (__attribute__((address_space(3))) void*)la, 16, 0, 0);
      __builtin_amdgcn_global_load_lds((__attribute__((address_space(1))) void*)gb,
                                       (__attribute__((address_space(3))) void*)lb, 16, 0, 0);
    }
  };

  // prologue: tile 0 -> buf 0
  stage(0, 0);
  __builtin_amdgcn_sched_barrier(0);
  asm volatile("s_waitcnt vmcnt(0)" ::: "memory");
  __builtin_amdgcn_sched_barrier(0);
  __builtin_amdgcn_s_barrier();
  __builtin_amdgcn_sched_barrier(0);

  for (int kt = 0; kt < nkt; ++kt) {
    const int cur = kt & 1;
    // prefetch next tile FIRST: its HBM latency hides under this tile's 64 MFMA
    if (kt + 1 < nkt) stage(kt + 1, cur ^ 1);
    __builtin_amdgcn_sched_barrier(0);
    const u16b* bufA = lds + cur * 32768;
    const u16b* bufB = bufA + 16384;
#pragma unroll
    for (int kk = 0; kk < 2; ++kk) {
      bf16x8 af[8], bfr[4];
#pragma unroll
      for (int m = 0; m < 8; ++m) {
        int r = wr * 128 + m * 16 + lr;
        int sidx = (kk * 4 + g0) ^ (r & 7);
        af[m] = *(const bf16x8*)&bufA[(r * 8 + sidx) * 8];
      }
#pragma unroll
      for (int n = 0; n < 4; ++n) {
        int r = wc * 64 + n * 16 + lr;
        int sidx = (kk * 4 + g0) ^ (r & 7);
        bfr[n] = *(const bf16x8*)&bufB[(r * 8 + sidx) * 8];
      }
      __builtin_amdgcn_s_setprio(1);
#pragma unroll
      for (int m = 0; m < 8; ++m)
#pragma unroll
        for (int n = 0; n < 4; ++n)
          acc[m][n] = __builtin_amdgcn_mfma_f32_16x16x32_bf16(af[m], bfr[n], acc[m][n], 0, 0, 0);
      __builtin_amdgcn_s_setprio(0);
    }
    // drain own prefetch loads, then raw barrier (no compiler full-drain)
    __builtin_amdgcn_sched_barrier(0);
    asm volatile("s_waitcnt vmcnt(0)" ::: "memory");
    __builtin_amdgcn_sched_barrier(0);
    __builtin_amdgcn_s_barrier();
    __builtin_amdgcn_sched_barrier(0);
  }

  // V^T epilogue: acc -> LDS (transposed, XOR-swizzled) -> coalesced write [batch][col][row]
  const bool doVT = (EPI == GEPI_BF16_VT) || (EPI == GEPI_QKV && z == 2);
  if (doVT) {
    u16b* tile = lds;
    u16b* vtb = (EPI == GEPI_QKV) ? (u16b*)(void*)pe : (u16b*)Cv;
#pragma unroll
    for (int m = 0; m < 8; ++m)
#pragma unroll
      for (int j = 0; j < 4; ++j) {
        int rl = wr * 128 + m * 16 + g0 * 4 + j;
#pragma unroll
        for (int n = 0; n < 4; ++n) {
          int cl = wc * 64 + n * 16 + lr;
          tile[cl * 256 + (rl ^ ((cl & 7) << 3))] = f2bf(acc[m][n][j]);
        }
      }
    __syncthreads();
    const int batch = m0 >> 11;
    const int r0b = m0 & (S_ - 1);
    u16b* obase = vtb + (size_t)batch * DM_ * S_ + r0b;
#pragma unroll
    for (int it = 0; it < 16; ++it) {
      int id = it * 512 + t;
      int c = id >> 5, rc = id & 31;
      *(bf16x8*)&obase[(size_t)(n0 + c) * S_ + rc * 8] =
          *(const bf16x8*)&tile[c * 256 + ((rc * 8) ^ ((c & 7) << 3))];
    }
    return;
  }

  u16b* Ch = (u16b*)Cv;
  float* Cf = (float*)Cv;
  const size_t cb = (size_t)(z >> 1) * sCb2 + (size_t)(z & 1) * sCb;
#pragma unroll
  for (int m = 0; m < 8; ++m) {
#pragma unroll
    for (int j = 0; j < 4; ++j) {
      int r = m0 + wr * 128 + m * 16 + g0 * 4 + j;
      size_t ro = cb + (size_t)r * sCr;
#pragma unroll
      for (int n = 0; n < 4; ++n) {
        int c = n0 + wc * 64 + n * 16 + lr;
        float v = acc[m][n][j];
        if constexpr (EPI == GEPI_BF16 || EPI == GEPI_QKV) Ch[ro + c] = f2bf(v);
        else if constexpr (EPI == GEPI_BIAS) Ch[ro + c] = f2bf(v + bias[c]);
        else if constexpr (EPI == GEPI_BIAS_PE)
          Ch[ro + c] = f2bf(v + bias[c] + pe[(size_t)(r & (S_ - 1)) * DM_ + c]);
        else if constexpr (EPI == GEPI_F32SCALE) Cf[ro + c] = v * alpha;
        else if constexpr (EPI == GEPI_BF16SCALE) Ch[ro + c] = f2bf(v * alpha);
        else Cf[ro + c] = v + bias[c];
      }
    }
  }
}

extern "C" void kernel_launch(void* const* d_in, const int* in_sizes, int n_in,
                              void* d_out, int out_size, void* d_ws, size_t ws_size,
                              hipStream_t stream) {
  const float* x     = (const float*)d_in[0];
  const float* W_in  = (const float*)d_in[1];
  const float* b_in  = (const float*)d_in[2];
  const float* W_ctx = (const float*)d_in[3];
  const float* b_ctx = (const float*)d_in[4];
  const float* Wq    = (const float*)d_in[5];
  const float* Wk    = (const float*)d_in[6];
  const float* Wv    = (const float*)d_in[7];
  const float* W_out = (const float*)d_in[8];
  const float* b_out = (const float*)d_in[9];
  float* out = (float*)d_out;

  const int LDS8 = 131072;
  hipFuncSetAttribute((const void*)gemm8<GEPI_BF16>,
                      hipFuncAttributeMaxDynamicSharedMemorySize, LDS8);
  hipFuncSetAttribute((const void*)gemm8<GEPI_BIAS>,
                      hipFuncAttributeMaxDynamicSharedMemorySize, LDS8);
  hipFuncSetAttribute((const void*)gemm8<GEPI_BIAS_PE>,
                      hipFuncAttributeMaxDynamicSharedMemorySize, LDS8);
  hipFuncSetAttribute((const void*)gemm8<GEPI_QKV>,
                      hipFuncAttributeMaxDynamicSharedMemorySize, LDS8);
  hipFuncSetAttribute((const void*)gemm8<GEPI_BF16SCALE>,
                      hipFuncAttributeMaxDynamicSharedMemorySize, LDS8);

  const size_t SZ_A12 = (size_t)2 * S_ * S_ * 4;       // 32 MB
  const size_t SZ_PF  = (size_t)B_ * S_ * S_ * 2;      // 64 MB full-batch bf16 P / A1
  const size_t SZ_H   = (size_t)MTOT * DM_ * 2;        // 32 MB
  const size_t SZ_WIN = (size_t)DM_ * DIN_ * 2;
  const size_t SZ_WX  = (size_t)DM_ * DM_ * 2;
  const size_t SZ_WO  = (size_t)DOUT_ * DM_ * 2;
  const size_t SZ_WL  = (size_t)3 * DM_ * DM_ * 2;
  const size_t SLACK  = 65536;
  const size_t needB = SZ_A12 + SZ_PF + 4 * SZ_H + SZ_WO + SZ_WL + SLACK;             // ~231.1 MB
  const size_t needC = SZ_A12 + 4 * SZ_H + SZ_WIN + SZ_WX + SZ_WO + SZ_WL + SLACK;    // ~170.1 MB
  bool fullP = ws_size >= needB;
  if (ws_size < needC) return;

  char* wsp = (char*)d_ws;
  size_t off = 0;
  auto alloc = [&](size_t bytes) -> void* {
    void* p = wsp + off;
    off += (bytes + 255) & ~(size_t)255;
    return p;
  };
  // fullP layout: Pfull | A12 | hbuf contiguous:
  //   A1 (8 batches bf16) -> Pfull (in-place softmax -> P)
  //   A2 (8 batches bf16) -> A12+hbuf (64 MB contiguous, both dead during scores)
  u16b* Pfull = fullP ? (u16b*)alloc(SZ_PF) : nullptr;
  float* A12  = (float*)alloc(SZ_A12);
  u16b* hbuf  = (u16b*)alloc(SZ_H);
  u16b* qbuf  = (u16b*)alloc(SZ_H);
  u16b* kbuf  = (u16b*)alloc(SZ_H);
  u16b* vtb   = (u16b*)alloc(SZ_H);
  u16b *winb, *wctxb;
  if (fullP) {   // head weights alias Pfull (dead until layer-0 scores)
    winb  = (u16b*)Pfull;
    wctxb = (u16b*)((char*)Pfull + SZ_WIN);
  } else {
    winb  = (u16b*)alloc(SZ_WIN);
    wctxb = (u16b*)alloc(SZ_WX);
  }
  u16b* woutb = (u16b*)alloc(SZ_WO);
  u16b* wTl   = (u16b*)alloc(SZ_WL);

  // xbf + pe alias A12 (dead before the attention phase)
  u16b* xbf = (u16b*)A12;
  float* pe = (float*)((char*)A12 + (size_t)MTOT * DIN_ * 2);
  float* A1f = A12;
  float* A2f = A12 + (size_t)S_ * S_;
  u16b* A2u  = (u16b*)A12;      // bf16 A2 region (spans A12+hbuf, 64 MB)

  const size_t WSTEP = (size_t)DM_ * DM_;
  u16b* wqTl = wTl;
  u16b* wkTl = wTl + WSTEP;
  u16b* wvTl = wTl + 2 * WSTEP;

  dim3 blk(256);

  pe_kernel<<<dim3((S_ * DM_) / 256), blk, 0, stream>>>(pe);
  cvt_bf16<<<dim3(2048), blk, 0, stream>>>(x, xbf, (long long)MTOT * DIN_);
  cvt_bf16<<<dim3(512), blk, 0, stream>>>(W_in, winb, (long long)DM_ * DIN_);
  cvt_bf16<<<dim3(1024), blk, 0, stream>>>(W_ctx, wctxb, (long long)DM_ * DM_);
  cvt_bf16<<<dim3(512), blk, 0, stream>>>(W_out, woutb, (long long)DOUT_ * DM_);

  // h1 = x @ W_in^T + b_in -> qbuf ; h = h1 @ W_ctx^T + b_ctx + PE -> hbuf
  gemm8<GEPI_BIAS><<<dim3(MTOT / 256, DM_ / 256, 1), dim3(512), LDS8, stream>>>(
      xbf, DIN_, 0, 0, winb, DIN_, 0, 0, qbuf, DM_, 0, 0, DIN_, b_in, nullptr, 1.0f);
  gemm8<GEPI_BIAS_PE><<<dim3(MTOT / 256, DM_ / 256, 1), dim3(512), LDS8, stream>>>(
      qbuf, DM_, 0, 0, wctxb, DM_, 0, 0, hbuf, DM_, 0, 0, DM_, b_ctx, pe, 1.0f);

  for (int l = 0; l < NL_; ++l) {
    tr3v2<<<dim3(DM_ / 64, DM_ / 64, 3), blk, 0, stream>>>(
        Wq + (size_t)l * WSTEP, Wk + (size_t)l * WSTEP, Wv + (size_t)l * WSTEP,
        wqTl, wkTl, wvTl);
    // Q, K, V projections in ONE z=3 launch (768 blocks = 3 full machine waves):
    // z=0 -> qbuf, z=1 -> kbuf (normal store); z=2 -> V^T epilogue to vtb (via pe slot)
    gemm8<GEPI_QKV><<<dim3(MTOT / 256, DM_ / 256, 3), dim3(512), LDS8, stream>>>(
        hbuf, DM_, 0, 0, wqTl, DM_, (long long)WSTEP, 2 * (long long)WSTEP,
        qbuf, DM_, (long long)(kbuf - qbuf), 0, DM_, nullptr, (const float*)vtb, 1.0f);

    if (fullP) {
      // all scores in ONE z=16 launch (1024 blocks): z=2b+half;
      // A1[b] -> Pfull + b*S*S, A2[b] -> A2u + b*S*S (spans A12|hbuf, both dead here)
      gemm8<GEPI_BF16SCALE><<<dim3(S_ / 256, S_ / 256, 16), dim3(512), LDS8, stream>>>(
          qbuf, DM_, DM_ / 2, (long long)S_ * DM_,
          kbuf, DM_, DM_ / 2, (long long)S_ * DM_,
          Pfull, S_, (long long)(A2u - Pfull), (long long)S_ * S_,
          DM_ / 2, nullptr, nullptr, 0.03125f);
      // one softmax over all 16384 rows; P in-place over A1 (Pfull)
      softmax_full<<<dim3(MTOT), blk, 0, stream>>>(Pfull, A2u);
      // h = P @ V, all batches in one 256-block launch
      gemm8<GEPI_BF16><<<dim3(S_ / 256, DM_ / 256, B_), dim3(512), LDS8, stream>>>(
          Pfull, S_, (long long)S_ * S_, 2 * (long long)S_ * S_,
          vtb, S_, (long long)DM_ * S_, 2 * (long long)DM_ * S_,
          hbuf, DM_, (long long)S_ * DM_, 2 * (long long)S_ * DM_,
          S_, nullptr, nullptr, 1.0f);
    } else {
      for (int b = 0; b < B_; ++b) {
        const u16b* qb = qbuf + (size_t)b * S_ * DM_;
        const u16b* kb = kbuf + (size_t)b * S_ * DM_;
        gemm_nt<GEPI_F32SCALE><<<dim3(S_ / 128, S_ / 128, 2), blk, 0, stream>>>(
            qb, DM_, DM_ / 2, kb, DM_, DM_ / 2,
            A1f, S_, (long long)S_ * S_, DM_ / 2, nullptr, nullptr, 0.03125f);
        softmax_combine<<<dim3(S_), blk, 0, stream>>>(A1f, A2f, (u16b*)A1f, 2 * S_);
        gemm_nt<GEPI_BF16><<<dim3(S_ / 128, DM_ / 128, 1), blk, 0, stream>>>(
            (u16b*)A1f, 2 * S_, 0, vtb + (size_t)b * DM_ * S_, S_, 0,
            hbuf + (size_t)b * S_ * DM_, DM_, 0, S_, nullptr, nullptr, 1.0f);
      }
    }
  }

  // out = h @ W_out^T + b_out (fp32)
  gemm_nt<GEPI_F32BIAS><<<dim3(MTOT / 128, DOUT_ / 128, 1), blk, 0, stream>>>(
      hbuf, DM_, 0, woutb, DM_, 0, out, DOUT_, 0, DM_, b_out, nullptr, 1.0f);
}